// Round 2
// baseline (590.516 us; speedup 1.0000x reference)
//
#include <hip/hip_runtime.h>

typedef unsigned int u32;
typedef __bf16 bf16x8 __attribute__((ext_vector_type(8)));
typedef float f32x4 __attribute__((ext_vector_type(4)));

#define B_DIM 4
#define E_DIM 200000
#define C_OUT 64
#define TPB   12500            // 16-edge tiles per batch
#define NT    (B_DIM * TPB)    // 50000 tiles
#define NBLK  1024             // exactly 4 blocks/CU co-resident (VGPR-limited)
#define NW    (NBLK * 4)       // 4096 waves; ~12-13 tiles per wave
#define WLDS_U4 1792           // weight LDS: 7 chunks * 4 quads * 64 outs uint4

// round-half-up bf16 pack of two floats -> packed u32 (lo in low half).
// float is sign-magnitude, so +0x8000 on the bit pattern rounds the magnitude.
__device__ __forceinline__ u32 pack_bf2(float lo, float hi) {
  u32 a = __float_as_uint(lo) + 0x8000u;
  u32 b = __float_as_uint(hi) + 0x8000u;
  return __builtin_amdgcn_perm(b, a, 0x07060302u);  // [hi16(b) : hi16(a)]
}

// |bf16(a_i) - bf16(b_i)| for a packed pair, result packed bf16.
__device__ __forceinline__ u32 absdiff_pack(u32 a, u32 b) {
  float alo = __uint_as_float(a << 16), ahi = __uint_as_float(a & 0xffff0000u);
  float blo = __uint_as_float(b << 16), bhi = __uint_as_float(b & 0xffff0000u);
  u32 dlo = __float_as_uint(alo - blo) + 0x8000u;
  u32 dhi = __float_as_uint(ahi - bhi) + 0x8000u;
  return __builtin_amdgcn_perm(dhi, dlo, 0x07060302u) & 0x7fff7fffu;
}

__device__ __forceinline__ uint4 absdiff_vec(uint4 a, uint4 b) {
  return make_uint4(absdiff_pack(a.x, b.x), absdiff_pack(a.y, b.y),
                    absdiff_pack(a.z, b.z), absdiff_pack(a.w, b.w));
}

// ---- kernel 1: x (B,C,E) f32 -> xT (B,E,C) packed bf16; row = 64 B ----------
// LDS-staged: both global reads and global writes fully coalesced. (proven)
__global__ __launch_bounds__(256) void xpose_kernel(const float* __restrict__ x,
                                                    u32* __restrict__ xT) {
  __shared__ u32 T[256 * 17];  // pitch 17: conflict-free scattered writes
  const int b = blockIdx.y;
  const int e0 = blockIdx.x * 256;
  const int t = threadIdx.x;
  const int nrows = min(256, E_DIM - e0);
  const float* xb = x + (size_t)b * 32 * E_DIM + e0;
  if (t < nrows) {
#pragma unroll
    for (int u = 0; u < 16; ++u) {
      const float lo = xb[(size_t)(2 * u) * E_DIM + t];      // coalesced
      const float hi = xb[(size_t)(2 * u + 1) * E_DIM + t];
      T[t * 17 + u] = pack_bf2(lo, hi);
    }
  }
  __syncthreads();
  const int total = nrows * 16;
  u32* dst = xT + ((size_t)b * E_DIM + e0) * 16;
#pragma unroll
  for (int k = 0; k < 16; ++k) {
    const int g = t + k * 256;
    if (g < total) dst[g] = T[(g >> 4) * 17 + (g & 15)];     // coalesced store
  }
}

// ---- kernel 2: MFMA main, 16 edges x 64 outs per wave-tile ------------------
// W swizzle + bias staged in LDS (prep_w merged into prologue; W is L2-hot).
// Identity gather layout: lane (n = l&15 edge, q = l>>4 quad) loads uint4 j4=q
// of the gathered row -> that register IS the MFMA B-fragment (no bpermute).
// 2-deep gather pipeline: g0 ready, g1/g2 in flight (cover ~2 iterations of
// latency), Gi indices 3 tiles ahead. Bias accumulator init comes from LDS
// each iteration so no persistent 16-reg bias cache (VGPR budget for g2).
__global__ __launch_bounds__(256, 4) void mesh_main(const u32* __restrict__ xT,
                                                    const int* __restrict__ Gi,
                                                    const float* __restrict__ W,
                                                    const float* __restrict__ bias,
                                                    float* __restrict__ out) {
  __shared__ uint4 Wl[WLDS_U4];  // 28 KB
  __shared__ float Bl[64];       // bias

  // ---- prologue: swizzled bf16 weights + bias -> LDS -----------------------
  // Wl_flat[((s*4+q)*64 + o)*4 + r] = pack(W[o][q*8+2r][kk], W[o][q*8+2r+1][kk])
  // K-chunks s=0..6 multiply {f0, f1, f2, f3, f4, |f1-f3|, |f2-f4|}
  {
    u32* wl = (u32*)&Wl[0];
#pragma unroll
    for (int k = 0; k < 28; ++k) {
      const int p = (int)threadIdx.x + k * 256;  // < 7168
      const int r = p & 3;
      const int o = (p >> 2) & 63;
      const int qq = (p >> 8) & 3;
      const int s = p >> 10;
      const int kk = s < 3 ? s : s - 2;          // {0,1,2,1,2,3,4}
      const int c0 = qq * 8 + 2 * r;
      const float w0 = W[(o * 32 + c0) * 5 + kk];
      const float w1 = W[(o * 32 + c0 + 1) * 5 + kk];
      wl[p] = pack_bf2(w0, w1);
    }
    if (threadIdx.x < 64) Bl[threadIdx.x] = bias[threadIdx.x];
  }
  __syncthreads();

  const int l = (int)threadIdx.x & 63;
  const int wv = (int)threadIdx.x >> 6;
  const int n = l & 15;   // edge-in-tile == B-frag column
  const int q = l >> 4;   // quad == gather j4 == B-frag k-group

  const uint4* xb4 = (const uint4*)xT;
  int t0 = blockIdx.x * 4 + wv;   // < 4096 < NT always

  // ---- pipeline prologue: gathers for t0, t0+NW in flight; Gi for t0+2NW ---
  int idxn[5];
  uint4 g0[5], g1[5];
  {
    const int b = t0 / TPB;
    const int e = (t0 - b * TPB) * 16 + n;
    const int* gp = Gi + (b * E_DIM + e) * 5;
    int ia[5];
#pragma unroll
    for (int s = 0; s < 5; ++s) ia[s] = b * E_DIM + gp[s];
#pragma unroll
    for (int s = 0; s < 5; ++s) g0[s] = xb4[(size_t)ia[s] * 4 + q];
  }
  {
    const int t1 = t0 + NW;  // < 8192 < NT always
    const int b = t1 / TPB;
    const int e = (t1 - b * TPB) * 16 + n;
    const int* gp = Gi + (b * E_DIM + e) * 5;
    int ib[5];
#pragma unroll
    for (int s = 0; s < 5; ++s) ib[s] = b * E_DIM + gp[s];
#pragma unroll
    for (int s = 0; s < 5; ++s) g1[s] = xb4[(size_t)ib[s] * 4 + q];
  }
  {
    const int t2 = t0 + 2 * NW;  // < 12288 < NT always
    const int b = t2 / TPB;
    const int e = (t2 - b * TPB) * 16 + n;
    const int* gp = Gi + (b * E_DIM + e) * 5;
#pragma unroll
    for (int s = 0; s < 5; ++s) idxn[s] = b * E_DIM + gp[s];
  }

  for (;;) {
    const bool has1 = (t0 + NW) < NT;       // g1 valid          (wave-uniform)
    const bool has2 = (t0 + 2 * NW) < NT;   // idxn valid -> issue g2

    // stage B: gather tile t0+2NW (indices resident for >=1 iteration)
    uint4 g2[5];
    if (has2) {
#pragma unroll
      for (int s = 0; s < 5; ++s) g2[s] = xb4[(size_t)idxn[s] * 4 + q];
    }
    // stage A: Gi indices for tile t0+3NW
    const int t3 = t0 + 3 * NW;
    if (t3 < NT) {
      const int b = t3 / TPB;
      const int e = (t3 - b * TPB) * 16 + n;
      const int* gp = Gi + (b * E_DIM + e) * 5;
#pragma unroll
      for (int s = 0; s < 5; ++s) idxn[s] = b * E_DIM + gp[s];
    }

    // stage C: compute tile t0 from g0 (issued 2 iterations ago)
    union U { uint4 u; bf16x8 v; };
    U f5, f6;
    f5.u = absdiff_vec(g0[1], g0[3]);
    f6.u = absdiff_vec(g0[2], g0[4]);

    f32x4 acc0 = *(const f32x4*)&Bl[0 * 16 + q * 4];
    f32x4 acc1 = *(const f32x4*)&Bl[1 * 16 + q * 4];
    f32x4 acc2 = *(const f32x4*)&Bl[2 * 16 + q * 4];
    f32x4 acc3 = *(const f32x4*)&Bl[3 * 16 + q * 4];
#pragma unroll
    for (int c = 0; c < 7; ++c) {
      U fr;
      if (c < 5) fr.u = g0[c];
      else if (c == 5) fr = f5;
      else fr = f6;
      const uint4* wp = Wl + (c * 4 + q) * 64 + n;
      U a0, a1;
      a0.u = wp[0];
      a1.u = wp[16];
      acc0 = __builtin_amdgcn_mfma_f32_16x16x32_bf16(a0.v, fr.v, acc0, 0, 0, 0);
      acc1 = __builtin_amdgcn_mfma_f32_16x16x32_bf16(a1.v, fr.v, acc1, 0, 0, 0);
      a0.u = wp[32];
      a1.u = wp[48];
      acc2 = __builtin_amdgcn_mfma_f32_16x16x32_bf16(a0.v, fr.v, acc2, 0, 0, 0);
      acc3 = __builtin_amdgcn_mfma_f32_16x16x32_bf16(a1.v, fr.v, acc3, 0, 0, 0);
    }

    // store: o = og*16 + q*4 + r, e = e0 + n
    {
      const int b = t0 / TPB;
      const int e0 = (t0 - b * TPB) * 16;
      float* ob = out + ((size_t)(b * C_OUT + q * 4) * E_DIM + e0 + n);
#pragma unroll
      for (int r = 0; r < 4; ++r) {
        ob[(size_t)(0 * 16 + r) * E_DIM] = acc0[r];
        ob[(size_t)(1 * 16 + r) * E_DIM] = acc1[r];
        ob[(size_t)(2 * 16 + r) * E_DIM] = acc2[r];
        ob[(size_t)(3 * 16 + r) * E_DIM] = acc3[r];
      }
    }

    if (!has1) break;
    t0 += NW;
#pragma unroll
    for (int s = 0; s < 5; ++s) { g0[s] = g1[s]; g1[s] = g2[s]; }
  }
}

extern "C" void kernel_launch(void* const* d_in, const int* in_sizes, int n_in,
                              void* d_out, int out_size, void* d_ws, size_t ws_size,
                              hipStream_t stream) {
  const float* x    = (const float*)d_in[0];
  const int*   Gi   = (const int*)d_in[1];
  const float* W    = (const float*)d_in[2];
  const float* bias = (const float*)d_in[3];
  float* out = (float*)d_out;

  // workspace: xT packed-bf16 rows (B*E*16 u32 = 51.2 MB)
  u32* xT = (u32*)d_ws;

  dim3 gx((E_DIM + 255) / 256, B_DIM);
  xpose_kernel<<<gx, 256, 0, stream>>>(x, xT);

  mesh_main<<<NBLK, 256, 0, stream>>>(xT, Gi, W, bias, out);
}

// Round 3
// 404.363 us; speedup vs baseline: 1.4604x; 1.4604x over previous
//
#include <hip/hip_runtime.h>

typedef unsigned int u32;
typedef __bf16 bf16x8 __attribute__((ext_vector_type(8)));
typedef float f32x4 __attribute__((ext_vector_type(4)));

#define B_DIM 4
#define E_DIM 200000
#define C_OUT 64
#define TPB   12500            // 16-edge tiles per batch
#define NT    (B_DIM * TPB)    // 50000 tiles
#define NBLK  1024             // exactly 4 blocks/CU co-resident, no tail
#define NW    (NBLK * 4)       // 4096 waves; ~12.2 tiles per wave
#define WLDS_U4 1792           // weight LDS: 7 chunks * 4 quads * 64 outs uint4

// round-half-up bf16 pack of two floats -> packed u32 (lo in low half).
// float is sign-magnitude, so +0x8000 on the bit pattern rounds the magnitude.
__device__ __forceinline__ u32 pack_bf2(float lo, float hi) {
  u32 a = __float_as_uint(lo) + 0x8000u;
  u32 b = __float_as_uint(hi) + 0x8000u;
  return __builtin_amdgcn_perm(b, a, 0x07060302u);  // [hi16(b) : hi16(a)]
}

// |bf16(a_i) - bf16(b_i)| for a packed pair, result packed bf16.
__device__ __forceinline__ u32 absdiff_pack(u32 a, u32 b) {
  float alo = __uint_as_float(a << 16), ahi = __uint_as_float(a & 0xffff0000u);
  float blo = __uint_as_float(b << 16), bhi = __uint_as_float(b & 0xffff0000u);
  u32 dlo = __float_as_uint(alo - blo) + 0x8000u;
  u32 dhi = __float_as_uint(ahi - bhi) + 0x8000u;
  return __builtin_amdgcn_perm(dhi, dlo, 0x07060302u) & 0x7fff7fffu;
}

__device__ __forceinline__ uint4 absdiff_vec(uint4 a, uint4 b) {
  return make_uint4(absdiff_pack(a.x, b.x), absdiff_pack(a.y, b.y),
                    absdiff_pack(a.z, b.z), absdiff_pack(a.w, b.w));
}

// ---- kernel 1: x (B,C,E) f32 -> xT (B,E,C) packed bf16; row = 64 B ----------
// LDS-staged: both global reads and global writes fully coalesced. (proven)
__global__ __launch_bounds__(256) void xpose_kernel(const float* __restrict__ x,
                                                    u32* __restrict__ xT) {
  __shared__ u32 T[256 * 17];  // pitch 17: conflict-free scattered writes
  const int b = blockIdx.y;
  const int e0 = blockIdx.x * 256;
  const int t = threadIdx.x;
  const int nrows = min(256, E_DIM - e0);
  const float* xb = x + (size_t)b * 32 * E_DIM + e0;
  if (t < nrows) {
#pragma unroll
    for (int u = 0; u < 16; ++u) {
      const float lo = xb[(size_t)(2 * u) * E_DIM + t];      // coalesced
      const float hi = xb[(size_t)(2 * u + 1) * E_DIM + t];
      T[t * 17 + u] = pack_bf2(lo, hi);
    }
  }
  __syncthreads();
  const int total = nrows * 16;
  u32* dst = xT + ((size_t)b * E_DIM + e0) * 16;
#pragma unroll
  for (int k = 0; k < 16; ++k) {
    const int g = t + k * 256;
    if (g < total) dst[g] = T[(g >> 4) * 17 + (g & 15)];     // coalesced store
  }
}

// ---- kernel 2: MFMA main, 16 edges x 64 outs per wave-tile ------------------
// Round-0 proven structure (1-deep gather pipeline):
//   stage B: gather tile t1 (indices resident)  stage A: Gi for t1+NW
//   stage C: compute tile t                     then shift.
// prep_w merged into prologue (W swizzle built directly in LDS, proven r1).
// Bias staged in LDS (keeps VGPR <= ~112; r2 proved the failure was the
// launch_bounds(,4) VGPR cap -> 64 regs -> spills, NOT the LDS bias).
// NOTE: no 2nd __launch_bounds__ arg -- (256,4) empirically forced 64 VGPRs.
__global__ __launch_bounds__(256) void mesh_main(const u32* __restrict__ xT,
                                                 const int* __restrict__ Gi,
                                                 const float* __restrict__ W,
                                                 const float* __restrict__ bias,
                                                 float* __restrict__ out) {
  __shared__ uint4 Wl[WLDS_U4];  // 28 KB
  __shared__ float Bl[64];       // bias

  // ---- prologue: swizzled bf16 weights + bias -> LDS -----------------------
  // Wl_flat[((s*4+q)*64 + o)*4 + r] = pack(W[o][q*8+2r][kk], W[o][q*8+2r+1][kk])
  // K-chunks s=0..6 multiply {f0, f1, f2, f3, f4, |f1-f3|, |f2-f4|}
  {
    u32* wl = (u32*)&Wl[0];
#pragma unroll
    for (int k = 0; k < 28; ++k) {
      const int p = (int)threadIdx.x + k * 256;  // < 7168
      const int r = p & 3;
      const int o = (p >> 2) & 63;
      const int qq = (p >> 8) & 3;
      const int s = p >> 10;
      const int kk = s < 3 ? s : s - 2;          // {0,1,2,1,2,3,4}
      const int c0 = qq * 8 + 2 * r;
      const float w0 = W[(o * 32 + c0) * 5 + kk];
      const float w1 = W[(o * 32 + c0 + 1) * 5 + kk];
      wl[p] = pack_bf2(w0, w1);
    }
    if (threadIdx.x < 64) Bl[threadIdx.x] = bias[threadIdx.x];
  }
  __syncthreads();

  const int l = (int)threadIdx.x & 63;
  const int wv = (int)threadIdx.x >> 6;
  const int n = l & 15;   // edge-in-tile == B-frag column
  const int q = l >> 4;   // quad == gather j4 == B-frag k-group

  const uint4* xb4 = (const uint4*)xT;

  int t = blockIdx.x * 4 + wv;          // < 4096 < NT always

  // ---- pipeline prologue: Gi(t) -> gather(t) -> Gi(t+NW) ----
  int gcur[5], gnext[5];
  {
    const int b = t / TPB;
    const int e = (t - b * TPB) * 16 + n;
    const int* gp = Gi + (b * E_DIM + e) * 5;
#pragma unroll
    for (int s = 0; s < 5; ++s) gcur[s] = b * E_DIM + gp[s];
  }
  uint4 cur[5];
#pragma unroll
  for (int s = 0; s < 5; ++s) cur[s] = xb4[(size_t)gcur[s] * 4 + q];

  int t1 = t + NW;
  if (t1 < NT) {
    const int b = t1 / TPB;
    const int e = (t1 - b * TPB) * 16 + n;
    const int* gp = Gi + (b * E_DIM + e) * 5;
#pragma unroll
    for (int s = 0; s < 5; ++s) gnext[s] = b * E_DIM + gp[s];
  }

  for (;;) {
    const bool has = t1 < NT;  // wave-uniform
    // stage B: gather tile t1 (Gi already resident for >=1 iteration)
    uint4 nxt[5];
    if (has) {
#pragma unroll
      for (int s = 0; s < 5; ++s) nxt[s] = xb4[(size_t)gnext[s] * 4 + q];
    }
    // stage A: Gi for tile t1+NW
    const int t2 = t1 + NW;
    if (t2 < NT) {
      const int b = t2 / TPB;
      const int e = (t2 - b * TPB) * 16 + n;
      const int* gp = Gi + (b * E_DIM + e) * 5;
#pragma unroll
      for (int s = 0; s < 5; ++s) gnext[s] = b * E_DIM + gp[s];
    }

    // stage C: compute tile t
    union U { uint4 u; bf16x8 v; };
    U frag[7];
#pragma unroll
    for (int s = 0; s < 5; ++s) frag[s].u = cur[s];
    frag[5].u = absdiff_vec(cur[1], cur[3]);
    frag[6].u = absdiff_vec(cur[2], cur[4]);

    f32x4 acc0 = *(const f32x4*)&Bl[0 * 16 + q * 4];
    f32x4 acc1 = *(const f32x4*)&Bl[1 * 16 + q * 4];
    f32x4 acc2 = *(const f32x4*)&Bl[2 * 16 + q * 4];
    f32x4 acc3 = *(const f32x4*)&Bl[3 * 16 + q * 4];
#pragma unroll
    for (int c = 0; c < 7; ++c) {
      const uint4* wp = Wl + (c * 4 + q) * 64 + n;
      U a0, a1;
      a0.u = wp[0];
      a1.u = wp[16];
      acc0 = __builtin_amdgcn_mfma_f32_16x16x32_bf16(a0.v, frag[c].v, acc0, 0, 0, 0);
      acc1 = __builtin_amdgcn_mfma_f32_16x16x32_bf16(a1.v, frag[c].v, acc1, 0, 0, 0);
      a0.u = wp[32];
      a1.u = wp[48];
      acc2 = __builtin_amdgcn_mfma_f32_16x16x32_bf16(a0.v, frag[c].v, acc2, 0, 0, 0);
      acc3 = __builtin_amdgcn_mfma_f32_16x16x32_bf16(a1.v, frag[c].v, acc3, 0, 0, 0);
    }

    // store: o = og*16 + q*4 + r, e = e0 + n
    {
      const int b = t / TPB;
      const int e0 = (t - b * TPB) * 16;
      float* ob = out + ((size_t)(b * C_OUT + q * 4) * E_DIM + e0 + n);
#pragma unroll
      for (int r = 0; r < 4; ++r) {
        ob[(size_t)(0 * 16 + r) * E_DIM] = acc0[r];
        ob[(size_t)(1 * 16 + r) * E_DIM] = acc1[r];
        ob[(size_t)(2 * 16 + r) * E_DIM] = acc2[r];
        ob[(size_t)(3 * 16 + r) * E_DIM] = acc3[r];
      }
    }

    if (!has) break;
    t = t1;
    t1 = t2;
#pragma unroll
    for (int s = 0; s < 5; ++s) cur[s] = nxt[s];
  }
}

extern "C" void kernel_launch(void* const* d_in, const int* in_sizes, int n_in,
                              void* d_out, int out_size, void* d_ws, size_t ws_size,
                              hipStream_t stream) {
  const float* x    = (const float*)d_in[0];
  const int*   Gi   = (const int*)d_in[1];
  const float* W    = (const float*)d_in[2];
  const float* bias = (const float*)d_in[3];
  float* out = (float*)d_out;

  // workspace: xT packed-bf16 rows (B*E*16 u32 = 51.2 MB)
  u32* xT = (u32*)d_ws;

  dim3 gx((E_DIM + 255) / 256, B_DIM);
  xpose_kernel<<<gx, 256, 0, stream>>>(x, xT);

  mesh_main<<<NBLK, 256, 0, stream>>>(xT, Gi, W, bias, out);
}